// Round 1
// baseline (8292.722 us; speedup 1.0000x reference)
//
#include <hip/hip_runtime.h>
#include <hip/hip_bf16.h>
#include <math.h>

#define D_MODEL 192
#define D_INNER 384
#define D_STATE 16
#define DT_RANK 12
#define DEPTH   24
#define SEQL    257
#define BATCH   32
#define NTOK    (BATCH*SEQL)   // 8224
#define NPATCH  256

// ---------------- patch rearrange: x (B,3,256,256) -> Apatch (B*256, 768) ----------------
__global__ __launch_bounds__(256) void rearrange_k(const float* __restrict__ x, float* __restrict__ Ap) {
    size_t i = (size_t)blockIdx.x * 256 + threadIdx.x;
    const size_t total = (size_t)8192 * 768 / 4;
    if (i >= total) return;
    size_t o = i * 4;
    int bt  = (int)(o / 768);
    int rem = (int)(o % 768);
    int c  = rem >> 8;
    int r2 = rem & 255;
    int pi = r2 >> 4;
    int pj = r2 & 15;
    int b = bt >> 8;
    int t = bt & 255;
    int ph = t >> 4, pw = t & 15;
    size_t src = (((size_t)(b * 3 + c) * 256) + (size_t)(ph * 16 + pi)) * 256 + (pw * 16 + pj);
    *(float4*)(Ap + o) = *(const float4*)(x + src);
}

// ---------------- assemble: insert cls token, add patch bias + pos embed ----------------
__global__ __launch_bounds__(192) void assemble_k(const float* __restrict__ P, const float* __restrict__ pb,
                                                  const float* __restrict__ cls, const float* __restrict__ pos,
                                                  float* __restrict__ hb) {
    int o = threadIdx.x;
    int l = blockIdx.x;
    int b = blockIdx.y;
    float v;
    if (l == 128) {
        v = cls[o];
    } else {
        int t = (l < 128) ? l : l - 1;
        v = P[((size_t)b * 256 + t) * 192 + o] + pb[o];
    }
    hb[((size_t)b * SEQL + l) * 192 + o] = v + pos[l * 192 + o];
}

// ---------------- fused add + RMSNorm ----------------
// FINAL=0: res += h (writes back), out = rmsnorm(res)*w
// FINAL=1: r = res + h (no writeback), out = rmsnorm(r)*w
template<int FINAL>
__global__ __launch_bounds__(192) void addnorm_k(float* res, const float* __restrict__ h,
                                                 const float* __restrict__ w, float* __restrict__ out) {
    int row = blockIdx.x;
    int t = threadIdx.x;
    size_t idx = (size_t)row * 192 + t;
    float r = res[idx] + h[idx];
    if (!FINAL) res[idx] = r;
    float ss = r * r;
    #pragma unroll
    for (int o = 32; o > 0; o >>= 1) ss += __shfl_down(ss, o);
    __shared__ float ps[3];
    int wid = t >> 6;
    if ((t & 63) == 0) ps[wid] = ss;
    __syncthreads();
    float tot = ps[0] + ps[1] + ps[2];
    float inv = rsqrtf(tot / 192.f + 1e-5f);
    out[idx] = r * inv * w[t];
}

// ---------------- generic fp32 GEMM: C[M,N] = A[M,K] * B[N,K]^T (both K-contiguous) ----------------
// EPI 0: none.  EPI 1: softplus(v + bias[n])
__device__ __forceinline__ float softplus_f(float v) {
    return (v > 20.f) ? v : log1pf(expf(v));
}

template<int EPI>
__global__ __launch_bounds__(256) void gemm_nt(const float* __restrict__ A, int lda,
                                               const float* __restrict__ Bw, int ldb,
                                               float* __restrict__ C, int ldc,
                                               int M, int N, int K, const float* __restrict__ bias) {
    const int BM = 64, BN = 64, BK = 16;
    __shared__ float As[BK][BM + 4];
    __shared__ float Bs[BK][BN + 4];
    int m0 = blockIdx.y * BM, n0 = blockIdx.x * BN;
    int tid = threadIdx.x;
    int lr = tid >> 2, lk = (tid & 3) * 4;
    int tx = tid & 15, ty = tid >> 4;
    float acc[4][4] = {};
    for (int k0 = 0; k0 < K; k0 += BK) {
        {
            int m = m0 + lr, k = k0 + lk;
            float4 v = make_float4(0.f, 0.f, 0.f, 0.f);
            if (m < M && k < K) v = *(const float4*)(A + (size_t)m * lda + k);
            As[lk + 0][lr] = v.x; As[lk + 1][lr] = v.y; As[lk + 2][lr] = v.z; As[lk + 3][lr] = v.w;
            int n = n0 + lr;
            float4 wv = make_float4(0.f, 0.f, 0.f, 0.f);
            if (n < N && k < K) wv = *(const float4*)(Bw + (size_t)n * ldb + k);
            Bs[lk + 0][lr] = wv.x; Bs[lk + 1][lr] = wv.y; Bs[lk + 2][lr] = wv.z; Bs[lk + 3][lr] = wv.w;
        }
        __syncthreads();
        #pragma unroll
        for (int kk = 0; kk < BK; kk++) {
            float4 a  = *(const float4*)&As[kk][ty * 4];
            float4 bv = *(const float4*)&Bs[kk][tx * 4];
            float av[4] = {a.x, a.y, a.z, a.w};
            float bb[4] = {bv.x, bv.y, bv.z, bv.w};
            #pragma unroll
            for (int i2 = 0; i2 < 4; i2++)
                #pragma unroll
                for (int j = 0; j < 4; j++)
                    acc[i2][j] = fmaf(av[i2], bb[j], acc[i2][j]);
        }
        __syncthreads();
    }
    #pragma unroll
    for (int i2 = 0; i2 < 4; i2++) {
        int m = m0 + ty * 4 + i2;
        if (m >= M) continue;
        #pragma unroll
        for (int j = 0; j < 4; j++) {
            int n = n0 + tx * 4 + j;
            if (n >= N) continue;
            float v = acc[i2][j];
            if (EPI == 1) v = softplus_f(v + bias[n]);
            C[(size_t)m * ldc + n] = v;
        }
    }
}

// ---------------- causal depthwise conv (k=4) + SiLU, both directions ----------------
__global__ __launch_bounds__(384) void conv_silu_k(const float* __restrict__ xz,
                                                   const float* __restrict__ cw, const float* __restrict__ cb,
                                                   const float* __restrict__ cwb, const float* __restrict__ cbb,
                                                   float* __restrict__ xcf, float* __restrict__ xcr) {
    int d = threadIdx.x;
    int l = blockIdx.x;
    int b = blockIdx.y;
    int dir = blockIdx.z;
    const float* w = dir ? cwb : cw;
    const float* bias = dir ? cbb : cb;
    float wr[4];
    {
        float4 wv = *(const float4*)(w + d * 4);
        wr[0] = wv.x; wr[1] = wv.y; wr[2] = wv.z; wr[3] = wv.w;
    }
    float acc = bias[d];
    #pragma unroll
    for (int k = 0; k < 4; k++) {
        int j = l - 3 + k;                    // position in (possibly flipped) sequence
        if (j < 0) continue;
        int lsrc = dir ? (SEQL - 1 - j) : j;
        float xv = xz[((size_t)b * SEQL + lsrc) * 768 + d];
        acc = fmaf(wr[k], xv, acc);
    }
    float s = acc / (1.f + expf(-acc));
    float* out = dir ? xcr : xcf;
    out[((size_t)b * SEQL + l) * 384 + d] = s;
}

// ---------------- selective scan, 1 thread per (b, d, dir), 16 states in regs ----------------
// dt buffers are overwritten in-place with y = (scan_y + D*xc) * silu(z)
__global__ __launch_bounds__(128) void scan_k(float* dtf, float* dtr,
                                              const float* __restrict__ xcf, const float* __restrict__ xcr,
                                              const float* __restrict__ dtbcf, const float* __restrict__ dtbcr,
                                              const float* __restrict__ xz,
                                              const float* __restrict__ Alf, const float* __restrict__ Alb,
                                              const float* __restrict__ Df, const float* __restrict__ Db) {
    int d = blockIdx.x * 128 + threadIdx.x;
    int b = blockIdx.y;
    int dir = blockIdx.z;
    float* dty = dir ? dtr : dtf;
    const float* xcb = dir ? xcr : xcf;
    const float* pbc = dir ? dtbcr : dtbcf;
    const float* Alog = (dir ? Alb : Alf) + d * 16;
    float Dp = (dir ? Db : Df)[d];
    float A[D_STATE];
    #pragma unroll
    for (int n = 0; n < 16; n++) A[n] = -expf(Alog[n]);
    float h[D_STATE];
    #pragma unroll
    for (int n = 0; n < 16; n++) h[n] = 0.f;
    for (int l = 0; l < SEQL; l++) {
        size_t row = (size_t)b * SEQL + l;
        float dt = dty[row * 384 + d];
        float x  = xcb[row * 384 + d];
        size_t zrow = dir ? ((size_t)b * SEQL + (SEQL - 1 - l)) : row;
        float zv = xz[zrow * 768 + 384 + d];
        const float4* bc = (const float4*)(pbc + row * 44 + 12);
        float4 B0 = bc[0], B1 = bc[1], B2 = bc[2], B3 = bc[3];
        float4 C0 = bc[4], C1 = bc[5], C2 = bc[6], C3 = bc[7];
        float Bv[16] = {B0.x,B0.y,B0.z,B0.w, B1.x,B1.y,B1.z,B1.w,
                        B2.x,B2.y,B2.z,B2.w, B3.x,B3.y,B3.z,B3.w};
        float Cv[16] = {C0.x,C0.y,C0.z,C0.w, C1.x,C1.y,C1.z,C1.w,
                        C2.x,C2.y,C2.z,C2.w, C3.x,C3.y,C3.z,C3.w};
        float dtx = dt * x;
        float y = 0.f;
        #pragma unroll
        for (int n = 0; n < 16; n++) {
            float dA = __expf(dt * A[n]);
            h[n] = fmaf(h[n], dA, dtx * Bv[n]);
            y = fmaf(h[n], Cv[n], y);
        }
        y = fmaf(Dp, x, y);
        float sz = zv / (1.f + expf(-zv));
        dty[row * 384 + d] = y * sz;
    }
}

// ---------------- combine directions: yf[b,l] = 0.5*(yf[b,l] + yr[b,L-1-l]) ----------------
__global__ __launch_bounds__(384) void combine_k(float* yfm, const float* __restrict__ yrm) {
    int d = threadIdx.x;
    int l = blockIdx.x;
    int b = blockIdx.y;
    size_t i1 = ((size_t)b * SEQL + l) * 384 + d;
    size_t i2 = ((size_t)b * SEQL + (SEQL - 1 - l)) * 384 + d;
    yfm[i1] = 0.5f * (yfm[i1] + yrm[i2]);
}

extern "C" void kernel_launch(void* const* d_in, const int* in_sizes, int n_in,
                              void* d_out, int out_size, void* d_ws, size_t ws_size,
                              hipStream_t stream) {
    const float* x         = (const float*)d_in[0];
    const float* patch_w   = (const float*)d_in[1];
    const float* patch_b   = (const float*)d_in[2];
    const float* cls_token = (const float*)d_in[3];
    const float* pos_embed = (const float*)d_in[4];
    const float* norm_w    = (const float*)d_in[5];
    const float* in_proj_w = (const float*)d_in[6];
    const float* conv_w    = (const float*)d_in[7];
    const float* conv_b    = (const float*)d_in[8];
    const float* xproj_w   = (const float*)d_in[9];
    const float* dtproj_w  = (const float*)d_in[10];
    const float* dt_bias   = (const float*)d_in[11];
    const float* A_log     = (const float*)d_in[12];
    const float* Dskip     = (const float*)d_in[13];
    const float* conv_w_b  = (const float*)d_in[14];
    const float* conv_b_b  = (const float*)d_in[15];
    const float* xproj_w_b = (const float*)d_in[16];
    const float* dtproj_w_b= (const float*)d_in[17];
    const float* dt_bias_b = (const float*)d_in[18];
    const float* A_log_b   = (const float*)d_in[19];
    const float* Dskip_b   = (const float*)d_in[20];
    const float* out_proj_w= (const float*)d_in[21];
    const float* norm_f_w  = (const float*)d_in[22];

    float* ws = (float*)d_ws;
    size_t off = 0;
    float* res   = ws + off; off += (size_t)NTOK * 192;   // 1,579,008
    float* hn    = ws + off; off += (size_t)NTOK * 192;
    float* hbuf  = ws + off; off += (size_t)NTOK * 192;
    float* xz    = ws + off; off += (size_t)NTOK * 768;   // also Apatch (8192*768)
    float* xcf   = ws + off; off += (size_t)NTOK * 384;   // also Ppatch (8192*192)
    float* xcr   = ws + off; off += (size_t)NTOK * 384;
    float* dtf   = ws + off; off += (size_t)NTOK * 384;   // becomes y_f in-place
    float* dtr   = ws + off; off += (size_t)NTOK * 384;   // becomes y_r in-place
    float* dtbcf = ws + off; off += (size_t)NTOK * 44;    // 361,856 (44*4=176B rows, 16B aligned)
    float* dtbcr = ws + off; off += (size_t)NTOK * 44;

    float* Apatch = xz;
    float* Ppatch = xcf;

    // residual starts at zero
    hipMemsetAsync(res, 0, (size_t)NTOK * 192 * sizeof(float), stream);

    // patch embedding
    rearrange_k<<<6144, 256, 0, stream>>>(x, Apatch);
    gemm_nt<0><<<dim3(3, 128), 256, 0, stream>>>(Apatch, 768, patch_w, 768, Ppatch, 192,
                                                 8192, 192, 768, nullptr);
    assemble_k<<<dim3(SEQL, BATCH), 192, 0, stream>>>(Ppatch, patch_b, cls_token, pos_embed, hbuf);

    for (int i = 0; i < DEPTH; i++) {
        const float* nw   = norm_w + i * 192;
        const float* win  = in_proj_w + (size_t)i * 768 * 192;
        const float* cwf  = conv_w + (size_t)i * 384 * 4;
        const float* cbf  = conv_b + (size_t)i * 384;
        const float* cwr  = conv_w_b + (size_t)i * 384 * 4;
        const float* cbr  = conv_b_b + (size_t)i * 384;
        const float* xpf  = xproj_w + (size_t)i * 44 * 384;
        const float* xpr  = xproj_w_b + (size_t)i * 44 * 384;
        const float* dpf  = dtproj_w + (size_t)i * 384 * 12;
        const float* dpr  = dtproj_w_b + (size_t)i * 384 * 12;
        const float* dbf  = dt_bias + (size_t)i * 384;
        const float* dbr  = dt_bias_b + (size_t)i * 384;
        const float* alf  = A_log + (size_t)i * 384 * 16;
        const float* alr  = A_log_b + (size_t)i * 384 * 16;
        const float* dsf  = Dskip + (size_t)i * 384;
        const float* dsr  = Dskip_b + (size_t)i * 384;
        const float* wout = out_proj_w + (size_t)i * 192 * 384;

        addnorm_k<0><<<NTOK, 192, 0, stream>>>(res, hbuf, nw, hn);
        gemm_nt<0><<<dim3(12, 129), 256, 0, stream>>>(hn, 192, win, 192, xz, 768,
                                                      NTOK, 768, 192, nullptr);
        conv_silu_k<<<dim3(SEQL, BATCH, 2), 384, 0, stream>>>(xz, cwf, cbf, cwr, cbr, xcf, xcr);
        gemm_nt<0><<<dim3(1, 129), 256, 0, stream>>>(xcf, 384, xpf, 384, dtbcf, 44,
                                                     NTOK, 44, 384, nullptr);
        gemm_nt<0><<<dim3(1, 129), 256, 0, stream>>>(xcr, 384, xpr, 384, dtbcr, 44,
                                                     NTOK, 44, 384, nullptr);
        gemm_nt<1><<<dim3(6, 129), 256, 0, stream>>>(dtbcf, 44, dpf, 12, dtf, 384,
                                                     NTOK, 384, 12, dbf);
        gemm_nt<1><<<dim3(6, 129), 256, 0, stream>>>(dtbcr, 44, dpr, 12, dtr, 384,
                                                     NTOK, 384, 12, dbr);
        scan_k<<<dim3(3, BATCH, 2), 128, 0, stream>>>(dtf, dtr, xcf, xcr, dtbcf, dtbcr, xz,
                                                      alf, alr, dsf, dsr);
        combine_k<<<dim3(SEQL, BATCH), 384, 0, stream>>>(dtf, dtr);
        gemm_nt<0><<<dim3(3, 129), 256, 0, stream>>>(dtf, 384, wout, 384, hbuf, 192,
                                                     NTOK, 192, 384, nullptr);
    }

    addnorm_k<1><<<NTOK, 192, 0, stream>>>(res, hbuf, norm_f_w, (float*)d_out);
}

// Round 2
// 6065.956 us; speedup vs baseline: 1.3671x; 1.3671x over previous
//
#include <hip/hip_runtime.h>
#include <hip/hip_bf16.h>
#include <math.h>

#define D_MODEL 192
#define D_INNER 384
#define D_STATE 16
#define DT_RANK 12
#define DEPTH   24
#define SEQL    257
#define BATCH   32
#define NTOK    (BATCH*SEQL)   // 8224

typedef unsigned short ushort_t;
using bf16x8 = __attribute__((ext_vector_type(8))) short;
using f32x4  = __attribute__((ext_vector_type(4))) float;

__device__ __forceinline__ ushort_t f2b(float f) {
    __hip_bfloat16 h = __float2bfloat16(f);
    return reinterpret_cast<ushort_t&>(h);
}
__device__ __forceinline__ float b2f(ushort_t u) {
    __hip_bfloat16 h;
    reinterpret_cast<ushort_t&>(h) = u;
    return __bfloat162float(h);
}

// ---------------- fp32 -> bf16 conversion ----------------
__global__ __launch_bounds__(256) void convert_k(const float* __restrict__ in, ushort_t* __restrict__ out, int n) {
    int i = (blockIdx.x * 256 + threadIdx.x) * 4;
    if (i + 3 < n) {
        float4 v = *(const float4*)(in + i);
        ushort4 o;
        o.x = f2b(v.x); o.y = f2b(v.y); o.z = f2b(v.z); o.w = f2b(v.w);
        *(ushort4*)(out + i) = o;
    } else {
        for (int j = i; j < n; j++) out[j] = f2b(in[j]);
    }
}

// ---------------- patch rearrange: x (B,3,256,256) -> Apatch bf16 (B*256, 768) ----------------
__global__ __launch_bounds__(256) void rearrange_k(const float* __restrict__ x, ushort_t* __restrict__ Ap) {
    size_t i = (size_t)blockIdx.x * 256 + threadIdx.x;
    const size_t total = (size_t)8192 * 768 / 4;
    if (i >= total) return;
    size_t o = i * 4;
    int bt  = (int)(o / 768);
    int rem = (int)(o % 768);
    int c  = rem >> 8;
    int r2 = rem & 255;
    int pi = r2 >> 4;
    int pj = r2 & 15;
    int b = bt >> 8;
    int t = bt & 255;
    int ph = t >> 4, pw = t & 15;
    size_t src = (((size_t)(b * 3 + c) * 256) + (size_t)(ph * 16 + pi)) * 256 + (pw * 16 + pj);
    float4 v = *(const float4*)(x + src);
    ushort4 ov;
    ov.x = f2b(v.x); ov.y = f2b(v.y); ov.z = f2b(v.z); ov.w = f2b(v.w);
    *(ushort4*)(Ap + o) = ov;
}

// ---------------- assemble: insert cls token, add patch bias + pos embed ----------------
__global__ __launch_bounds__(192) void assemble_k(const float* __restrict__ P, const float* __restrict__ pb,
                                                  const float* __restrict__ cls, const float* __restrict__ pos,
                                                  float* __restrict__ hb) {
    int o = threadIdx.x;
    int l = blockIdx.x;
    int b = blockIdx.y;
    float v;
    if (l == 128) {
        v = cls[o];
    } else {
        int t = (l < 128) ? l : l - 1;
        v = P[((size_t)b * 256 + t) * 192 + o] + pb[o];
    }
    hb[((size_t)b * SEQL + l) * 192 + o] = v + pos[l * 192 + o];
}

// ---------------- fused add + RMSNorm ----------------
// FINAL=0: res += h (writeback), out bf16. FINAL=1: no writeback, out fp32.
template<int FINAL>
__global__ __launch_bounds__(192) void addnorm_k(float* res, const float* __restrict__ h,
                                                 const float* __restrict__ w, void* __restrict__ outp) {
    int row = blockIdx.x;
    int t = threadIdx.x;
    size_t idx = (size_t)row * 192 + t;
    float r = res[idx] + h[idx];
    if (!FINAL) res[idx] = r;
    float ss = r * r;
    #pragma unroll
    for (int o = 32; o > 0; o >>= 1) ss += __shfl_down(ss, o);
    __shared__ float ps[3];
    int wid = t >> 6;
    if ((t & 63) == 0) ps[wid] = ss;
    __syncthreads();
    float tot = ps[0] + ps[1] + ps[2];
    float inv = rsqrtf(tot / 192.f + 1e-5f);
    float v = r * inv * w[t];
    if (FINAL) ((float*)outp)[idx] = v;
    else       ((ushort_t*)outp)[idx] = f2b(v);
}

// ---------------- bf16 MFMA GEMM: C[M,N] fp32 = A[M,K]bf16 * W[N,K]bf16^T ----------------
// BM=128, BN=64, BK=32; 256 threads = 4 waves (2x2), wave tile 64x32 (4x2 of 16x16).
__global__ __launch_bounds__(256) void gemm_bf16(const ushort_t* __restrict__ A,
                                                 const ushort_t* __restrict__ W,
                                                 float* __restrict__ C,
                                                 int M, int N, int K, int ldc) {
    __shared__ ushort_t As[128 * 40];   // row stride 40 ushorts (80B) -> conflict-free-ish
    __shared__ ushort_t Bs[64 * 40];
    int tid = threadIdx.x;
    int m0 = blockIdx.y * 128, n0 = blockIdx.x * 64;
    int row = tid >> 2;              // 0..63
    int k8  = (tid & 3) * 8;         // 0,8,16,24
    int lane = tid & 63;
    int w = tid >> 6;
    int wr = w >> 1, wc = w & 1;
    int lr = lane & 15;
    int lk = (lane >> 4) * 8;
    f32x4 acc[4][2];
    #pragma unroll
    for (int i = 0; i < 4; i++)
        #pragma unroll
        for (int j = 0; j < 2; j++) acc[i][j] = (f32x4){0.f, 0.f, 0.f, 0.f};

    for (int k0 = 0; k0 < K; k0 += 32) {
        // stage A (two 64-row halves) and B
        #pragma unroll
        for (int hhalf = 0; hhalf < 2; hhalf++) {
            int r = row + hhalf * 64;
            int m = m0 + r;
            bf16x8 v = {0,0,0,0,0,0,0,0};
            if (m < M) v = *(const bf16x8*)(A + (size_t)m * K + k0 + k8);
            *(bf16x8*)(&As[r * 40 + k8]) = v;
        }
        {
            int n = n0 + row;
            bf16x8 v = {0,0,0,0,0,0,0,0};
            if (n < N) v = *(const bf16x8*)(W + (size_t)n * K + k0 + k8);
            *(bf16x8*)(&Bs[row * 40 + k8]) = v;
        }
        __syncthreads();
        bf16x8 af[4], bfr[2];
        #pragma unroll
        for (int mi = 0; mi < 4; mi++)
            af[mi] = *(const bf16x8*)(&As[(wr * 64 + mi * 16 + lr) * 40 + lk]);
        #pragma unroll
        for (int ni = 0; ni < 2; ni++)
            bfr[ni] = *(const bf16x8*)(&Bs[(wc * 32 + ni * 16 + lr) * 40 + lk]);
        #pragma unroll
        for (int mi = 0; mi < 4; mi++)
            #pragma unroll
            for (int ni = 0; ni < 2; ni++)
                acc[mi][ni] = __builtin_amdgcn_mfma_f32_16x16x32_bf16(af[mi], bfr[ni], acc[mi][ni], 0, 0, 0);
        __syncthreads();
    }
    int rbase = (lane >> 4) * 4;
    #pragma unroll
    for (int mi = 0; mi < 4; mi++) {
        #pragma unroll
        for (int ni = 0; ni < 2; ni++) {
            #pragma unroll
            for (int r = 0; r < 4; r++) {
                int m = m0 + wr * 64 + mi * 16 + rbase + r;
                int n = n0 + wc * 32 + ni * 16 + lr;
                if (m < M && n < N) C[(size_t)m * ldc + n] = acc[mi][ni][r];
            }
        }
    }
}

// ---------------- fp32 GEMM (kept for dt_proj): C = A * B^T, EPI1 = softplus(v+bias) ----------------
__device__ __forceinline__ float softplus_f(float v) {
    return (v > 20.f) ? v : log1pf(expf(v));
}

template<int EPI>
__global__ __launch_bounds__(256) void gemm_nt(const float* __restrict__ A, int lda,
                                               const float* __restrict__ Bw, int ldb,
                                               float* __restrict__ C, int ldc,
                                               int M, int N, int K, const float* __restrict__ bias) {
    const int BM = 64, BN = 64, BK = 16;
    __shared__ float As[BK][BM + 4];
    __shared__ float Bs[BK][BN + 4];
    int m0 = blockIdx.y * BM, n0 = blockIdx.x * BN;
    int tid = threadIdx.x;
    int lr = tid >> 2, lk = (tid & 3) * 4;
    int tx = tid & 15, ty = tid >> 4;
    float acc[4][4] = {};
    for (int k0 = 0; k0 < K; k0 += BK) {
        {
            int m = m0 + lr, k = k0 + lk;
            float4 v = make_float4(0.f, 0.f, 0.f, 0.f);
            if (m < M && k < K) v = *(const float4*)(A + (size_t)m * lda + k);
            As[lk + 0][lr] = v.x; As[lk + 1][lr] = v.y; As[lk + 2][lr] = v.z; As[lk + 3][lr] = v.w;
            int n = n0 + lr;
            float4 wv = make_float4(0.f, 0.f, 0.f, 0.f);
            if (n < N && k < K) wv = *(const float4*)(Bw + (size_t)n * ldb + k);
            Bs[lk + 0][lr] = wv.x; Bs[lk + 1][lr] = wv.y; Bs[lk + 2][lr] = wv.z; Bs[lk + 3][lr] = wv.w;
        }
        __syncthreads();
        #pragma unroll
        for (int kk = 0; kk < BK; kk++) {
            float4 a  = *(const float4*)&As[kk][ty * 4];
            float4 bv = *(const float4*)&Bs[kk][tx * 4];
            float av[4] = {a.x, a.y, a.z, a.w};
            float bb[4] = {bv.x, bv.y, bv.z, bv.w};
            #pragma unroll
            for (int i2 = 0; i2 < 4; i2++)
                #pragma unroll
                for (int j = 0; j < 4; j++)
                    acc[i2][j] = fmaf(av[i2], bb[j], acc[i2][j]);
        }
        __syncthreads();
    }
    #pragma unroll
    for (int i2 = 0; i2 < 4; i2++) {
        int m = m0 + ty * 4 + i2;
        if (m >= M) continue;
        #pragma unroll
        for (int j = 0; j < 4; j++) {
            int n = n0 + tx * 4 + j;
            if (n >= N) continue;
            float v = acc[i2][j];
            if (EPI == 1) v = softplus_f(v + bias[n]);
            C[(size_t)m * ldc + n] = v;
        }
    }
}

// ---------------- causal depthwise conv (k=4) + SiLU, both directions, bf16 out ----------------
__global__ __launch_bounds__(384) void conv_silu_k(const float* __restrict__ xz,
                                                   const float* __restrict__ cw, const float* __restrict__ cb,
                                                   const float* __restrict__ cwb, const float* __restrict__ cbb,
                                                   ushort_t* __restrict__ xcf, ushort_t* __restrict__ xcr) {
    int d = threadIdx.x;
    int l = blockIdx.x;
    int b = blockIdx.y;
    int dir = blockIdx.z;
    const float* w = dir ? cwb : cw;
    const float* bias = dir ? cbb : cb;
    float wr[4];
    {
        float4 wv = *(const float4*)(w + d * 4);
        wr[0] = wv.x; wr[1] = wv.y; wr[2] = wv.z; wr[3] = wv.w;
    }
    float acc = bias[d];
    #pragma unroll
    for (int k = 0; k < 4; k++) {
        int j = l - 3 + k;
        if (j < 0) continue;
        int lsrc = dir ? (SEQL - 1 - j) : j;
        float xv = xz[((size_t)b * SEQL + lsrc) * 768 + d];
        acc = fmaf(wr[k], xv, acc);
    }
    float s = acc / (1.f + expf(-acc));
    ushort_t* out = dir ? xcr : xcf;
    out[((size_t)b * SEQL + l) * 384 + d] = f2b(s);
}

// ---------------- selective scan: B/C staged in LDS, dt/x/z prefetched ----------------
// 64 threads/block, block = (dchunk, b, dir). dt buffer overwritten in-place with y*silu(z).
__global__ __launch_bounds__(64) void scan_k(float* dtf, float* dtr,
                                             const ushort_t* __restrict__ xcf, const ushort_t* __restrict__ xcr,
                                             const float* __restrict__ dtbcf, const float* __restrict__ dtbcr,
                                             const float* __restrict__ xz,
                                             const float* __restrict__ Alf, const float* __restrict__ Alb,
                                             const float* __restrict__ Df, const float* __restrict__ Db) {
    __shared__ float bcs[SEQL * 32];   // 32.9 KB: B[l][16], C[l][16]
    int tid = threadIdx.x;
    int d = blockIdx.x * 64 + tid;
    int b = blockIdx.y;
    int dir = blockIdx.z;
    float* dty = dir ? dtr : dtf;
    const ushort_t* xcb = dir ? xcr : xcf;
    const float* pbc = (dir ? dtbcr : dtbcf) + (size_t)b * SEQL * 44;
    const float* Alog = (dir ? Alb : Alf) + d * 16;
    float Dp = (dir ? Db : Df)[d];

    // stage B/C for all timesteps (coalesced float4 loads)
    for (int i = tid; i < SEQL * 8; i += 64) {
        int l = i >> 3, j = i & 7;
        float4 v = *(const float4*)(pbc + (size_t)l * 44 + 12 + j * 4);
        *(float4*)(&bcs[l * 32 + j * 4]) = v;
    }
    __syncthreads();

    float A[D_STATE];
    #pragma unroll
    for (int n = 0; n < 16; n++) A[n] = -expf(Alog[n]);
    float h[D_STATE];
    #pragma unroll
    for (int n = 0; n < 16; n++) h[n] = 0.f;

    size_t rowbase = (size_t)b * SEQL;
    // prefetch step 0
    float dt_c = dty[rowbase * 384 + d];
    float x_c  = b2f(xcb[rowbase * 384 + d]);
    float z_c;
    {
        size_t zrow = dir ? (rowbase + SEQL - 1) : rowbase;
        z_c = xz[zrow * 768 + 384 + d];
    }
    for (int l = 0; l < SEQL; l++) {
        // prefetch l+1 (clamped) — issues loads that hide under compute below
        int ln = (l + 1 < SEQL) ? (l + 1) : l;
        size_t rown = rowbase + ln;
        float dt_n = dty[rown * 384 + d];
        float x_n  = b2f(xcb[rown * 384 + d]);
        size_t zrown = dir ? (rowbase + SEQL - 1 - ln) : rown;
        float z_n = xz[zrown * 768 + 384 + d];

        float dt = dt_c, xv = x_c, zv = z_c;
        float dtx = dt * xv;
        const float* bc = &bcs[l * 32];
        float y = 0.f;
        #pragma unroll
        for (int n = 0; n < 16; n++) {
            float dA = __expf(dt * A[n]);
            h[n] = fmaf(h[n], dA, dtx * bc[n]);
            y = fmaf(h[n], bc[16 + n], y);
        }
        y = fmaf(Dp, xv, y);
        float sz = zv / (1.f + expf(-zv));
        dty[(rowbase + l) * 384 + d] = y * sz;

        dt_c = dt_n; x_c = x_n; z_c = z_n;
    }
}

// ---------------- combine directions -> bf16: y[b,l] = 0.5*(yf[b,l] + yr[b,L-1-l]) ----------------
__global__ __launch_bounds__(384) void combine_k(const float* __restrict__ yfm, const float* __restrict__ yrm,
                                                 ushort_t* __restrict__ yb) {
    int d = threadIdx.x;
    int l = blockIdx.x;
    int b = blockIdx.y;
    size_t i1 = ((size_t)b * SEQL + l) * 384 + d;
    size_t i2 = ((size_t)b * SEQL + (SEQL - 1 - l)) * 384 + d;
    yb[i1] = f2b(0.5f * (yfm[i1] + yrm[i2]));
}

extern "C" void kernel_launch(void* const* d_in, const int* in_sizes, int n_in,
                              void* d_out, int out_size, void* d_ws, size_t ws_size,
                              hipStream_t stream) {
    const float* x         = (const float*)d_in[0];
    const float* patch_w   = (const float*)d_in[1];
    const float* patch_b   = (const float*)d_in[2];
    const float* cls_token = (const float*)d_in[3];
    const float* pos_embed = (const float*)d_in[4];
    const float* norm_w    = (const float*)d_in[5];
    const float* in_proj_w = (const float*)d_in[6];
    const float* conv_w    = (const float*)d_in[7];
    const float* conv_b    = (const float*)d_in[8];
    const float* xproj_w   = (const float*)d_in[9];
    const float* dtproj_w  = (const float*)d_in[10];
    const float* dt_bias   = (const float*)d_in[11];
    const float* A_log     = (const float*)d_in[12];
    const float* Dskip     = (const float*)d_in[13];
    const float* conv_w_b  = (const float*)d_in[14];
    const float* conv_b_b  = (const float*)d_in[15];
    const float* xproj_w_b = (const float*)d_in[16];
    const float* dtproj_w_b= (const float*)d_in[17];
    const float* dt_bias_b = (const float*)d_in[18];
    const float* A_log_b   = (const float*)d_in[19];
    const float* Dskip_b   = (const float*)d_in[20];
    const float* out_proj_w= (const float*)d_in[21];
    const float* norm_f_w  = (const float*)d_in[22];

    float* ws = (float*)d_ws;
    size_t off = 0;
    float* res   = ws + off; off += (size_t)NTOK * 192;
    float* hbuf  = ws + off; off += (size_t)NTOK * 192;
    float* xz    = ws + off; off += (size_t)NTOK * 768;      // also Apatch bf16 (8192*768 ushorts)
    ushort_t* hnb = (ushort_t*)(ws + off); off += (size_t)NTOK * 192 / 2;
    ushort_t* xcfb = (ushort_t*)(ws + off); off += (size_t)NTOK * 384 / 2;   // also ybuf bf16
    ushort_t* xcrb = (ushort_t*)(ws + off); off += (size_t)NTOK * 384 / 2;
    float* dtf   = ws + off; off += (size_t)NTOK * 384;      // also Ppatch fp32 (8192*192)
    float* dtr   = ws + off; off += (size_t)NTOK * 384;
    float* dtbcf = ws + off; off += (size_t)NTOK * 44;
    float* dtbcr = ws + off; off += (size_t)NTOK * 44;
    ushort_t* wb = (ushort_t*)(ws + off);
    ushort_t* winb   = wb;                    // 24*768*192 = 3,538,944
    ushort_t* woutb  = winb  + 3538944;       // 24*192*384 = 1,769,472
    ushort_t* xpfb   = woutb + 1769472;       // 24*44*384  =   405,504
    ushort_t* xprb   = xpfb  + 405504;
    ushort_t* patchwb= xprb  + 405504;        // 192*768    =   147,456

    ushort_t* Apatch = (ushort_t*)xz;
    float* Ppatch = dtf;
    ushort_t* ybuf = xcfb;

    // weight conversions (fp32 -> bf16)
    convert_k<<<(3538944/4 + 255)/256, 256, 0, stream>>>(in_proj_w, winb, 3538944);
    convert_k<<<(1769472/4 + 255)/256, 256, 0, stream>>>(out_proj_w, woutb, 1769472);
    convert_k<<<(405504/4 + 255)/256, 256, 0, stream>>>(xproj_w, xpfb, 405504);
    convert_k<<<(405504/4 + 255)/256, 256, 0, stream>>>(xproj_w_b, xprb, 405504);
    convert_k<<<(147456/4 + 255)/256, 256, 0, stream>>>(patch_w, patchwb, 147456);

    hipMemsetAsync(res, 0, (size_t)NTOK * 192 * sizeof(float), stream);

    // patch embedding
    rearrange_k<<<6144, 256, 0, stream>>>(x, Apatch);
    gemm_bf16<<<dim3(3, 64), 256, 0, stream>>>(Apatch, patchwb, Ppatch, 8192, 192, 768, 192);
    assemble_k<<<dim3(SEQL, BATCH), 192, 0, stream>>>(Ppatch, patch_b, cls_token, pos_embed, hbuf);

    for (int i = 0; i < DEPTH; i++) {
        const float* nw   = norm_w + i * 192;
        const float* cwf  = conv_w + (size_t)i * 384 * 4;
        const float* cbf  = conv_b + (size_t)i * 384;
        const float* cwr  = conv_w_b + (size_t)i * 384 * 4;
        const float* cbr  = conv_b_b + (size_t)i * 384;
        const float* dpf  = dtproj_w + (size_t)i * 384 * 12;
        const float* dpr  = dtproj_w_b + (size_t)i * 384 * 12;
        const float* dbf  = dt_bias + (size_t)i * 384;
        const float* dbr  = dt_bias_b + (size_t)i * 384;
        const float* alf  = A_log + (size_t)i * 384 * 16;
        const float* alr  = A_log_b + (size_t)i * 384 * 16;
        const float* dsf  = Dskip + (size_t)i * 384;
        const float* dsr  = Dskip_b + (size_t)i * 384;

        addnorm_k<0><<<NTOK, 192, 0, stream>>>(res, hbuf, nw, hnb);
        gemm_bf16<<<dim3(12, 65), 256, 0, stream>>>(hnb, winb + (size_t)i * 768 * 192, xz,
                                                    NTOK, 768, 192, 768);
        conv_silu_k<<<dim3(SEQL, BATCH, 2), 384, 0, stream>>>(xz, cwf, cbf, cwr, cbr, xcfb, xcrb);
        gemm_bf16<<<dim3(1, 65), 256, 0, stream>>>(xcfb, xpfb + (size_t)i * 44 * 384, dtbcf,
                                                   NTOK, 44, 384, 44);
        gemm_bf16<<<dim3(1, 65), 256, 0, stream>>>(xcrb, xprb + (size_t)i * 44 * 384, dtbcr,
                                                   NTOK, 44, 384, 44);
        gemm_nt<1><<<dim3(6, 129), 256, 0, stream>>>(dtbcf, 44, dpf, 12, dtf, 384,
                                                     NTOK, 384, 12, dbf);
        gemm_nt<1><<<dim3(6, 129), 256, 0, stream>>>(dtbcr, 44, dpr, 12, dtr, 384,
                                                     NTOK, 384, 12, dbr);
        scan_k<<<dim3(6, BATCH, 2), 64, 0, stream>>>(dtf, dtr, xcfb, xcrb, dtbcf, dtbcr, xz,
                                                     alf, alr, dsf, dsr);
        combine_k<<<dim3(SEQL, BATCH), 384, 0, stream>>>(dtf, dtr, ybuf);
        gemm_bf16<<<dim3(3, 65), 256, 0, stream>>>(ybuf, woutb + (size_t)i * 192 * 384, hbuf,
                                                   NTOK, 192, 384, 192);
    }

    addnorm_k<1><<<NTOK, 192, 0, stream>>>(res, hbuf, norm_f_w, (float*)d_out);
}